// Round 3
// baseline (478.196 us; speedup 1.0000x reference)
//
#include <hip/hip_runtime.h>
#include <float.h>
#include <math.h>

#define D 128
#define FIVE_D 640
#define NOUT 128
#define GW 8  // gemm rows per wave

// ---------------- Kernel 1: segment offsets via binary search on sorted batch ----------------
__global__ void seg_offsets_kernel(const int* __restrict__ batch, int* __restrict__ offs,
                                   int N, int G) {
    int g = blockIdx.x * blockDim.x + threadIdx.x;
    if (g > G) return;
    if (g == G) { offs[G] = N; return; }
    int lo = 0, hi = N;
    while (lo < hi) {
        int mid = (lo + hi) >> 1;
        if (batch[mid] < g) lo = mid + 1; else hi = mid;
    }
    offs[g] = lo;
}

// ---------------- Kernel 2: per-segment stats -> feats[g][640] ----------------
// One wave per segment. half=lane>>5 picks even/odd row, c=lane&31 picks float4 col.
// 64 lanes x 16B = 2 rows per load instruction; 4 float4 loads (8 rows) in flight.
__global__ __launch_bounds__(64) void seg_stats_kernel(const float* __restrict__ x,
                                                       const int* __restrict__ offs,
                                                       float* __restrict__ feats) {
    const int g = blockIdx.x;
    const int lane = threadIdx.x;
    const int half = lane >> 5;
    const int c = lane & 31;
    const int start = offs[g];
    const int end   = offs[g + 1];

    float4 s  = make_float4(0.f, 0.f, 0.f, 0.f);
    float4 q  = make_float4(0.f, 0.f, 0.f, 0.f);
    float4 mn = make_float4(FLT_MAX, FLT_MAX, FLT_MAX, FLT_MAX);
    float4 mx = make_float4(-FLT_MAX, -FLT_MAX, -FLT_MAX, -FLT_MAX);

    const float4* xp = reinterpret_cast<const float4*>(x) + c;  // row r at xp[r*32]

    auto acc = [&](float4 v) {
        s.x += v.x; s.y += v.y; s.z += v.z; s.w += v.w;
        q.x = fmaf(v.x, v.x, q.x); q.y = fmaf(v.y, v.y, q.y);
        q.z = fmaf(v.z, v.z, q.z); q.w = fmaf(v.w, v.w, q.w);
        mn.x = fminf(mn.x, v.x); mn.y = fminf(mn.y, v.y);
        mn.z = fminf(mn.z, v.z); mn.w = fminf(mn.w, v.w);
        mx.x = fmaxf(mx.x, v.x); mx.y = fmaxf(mx.y, v.y);
        mx.z = fmaxf(mx.z, v.z); mx.w = fmaxf(mx.w, v.w);
    };

    int base = start;
    for (; base + 8 <= end; base += 8) {
        float4 v0 = xp[(size_t)(base + 0 + half) * 32];
        float4 v1 = xp[(size_t)(base + 2 + half) * 32];
        float4 v2 = xp[(size_t)(base + 4 + half) * 32];
        float4 v3 = xp[(size_t)(base + 6 + half) * 32];
        acc(v0); acc(v1); acc(v2); acc(v3);
    }
    for (; base + 2 <= end; base += 2) {
        float4 v = xp[(size_t)(base + half) * 32];
        acc(v);
    }
    if (base < end && half == 0) {
        float4 v = xp[(size_t)base * 32];
        acc(v);
    }

    s.x += __shfl_xor(s.x, 32); s.y += __shfl_xor(s.y, 32);
    s.z += __shfl_xor(s.z, 32); s.w += __shfl_xor(s.w, 32);
    q.x += __shfl_xor(q.x, 32); q.y += __shfl_xor(q.y, 32);
    q.z += __shfl_xor(q.z, 32); q.w += __shfl_xor(q.w, 32);
    mn.x = fminf(mn.x, __shfl_xor(mn.x, 32)); mn.y = fminf(mn.y, __shfl_xor(mn.y, 32));
    mn.z = fminf(mn.z, __shfl_xor(mn.z, 32)); mn.w = fminf(mn.w, __shfl_xor(mn.w, 32));
    mx.x = fmaxf(mx.x, __shfl_xor(mx.x, 32)); mx.y = fmaxf(mx.y, __shfl_xor(mx.y, 32));
    mx.z = fmaxf(mx.z, __shfl_xor(mx.z, 32)); mx.w = fmaxf(mx.w, __shfl_xor(mx.w, 32));

    if (half == 0) {
        const float cnt = (float)max(end - start, 1);
        const float inv = 1.0f / cnt;
        const float SC = 0.14142135623730950488f;  // 1/sqrt(50)
        float4 mean = make_float4(s.x * inv, s.y * inv, s.z * inv, s.w * inv);
        float4 sd;
        sd.x = sqrtf(fmaxf(q.x * inv - mean.x * mean.x, 1e-9f));
        sd.y = sqrtf(fmaxf(q.y * inv - mean.y * mean.y, 1e-9f));
        sd.z = sqrtf(fmaxf(q.z * inv - mean.z * mean.z, 1e-9f));
        sd.w = sqrtf(fmaxf(q.w * inv - mean.w * mean.w, 1e-9f));
        float4 ssc = make_float4(s.x * SC, s.y * SC, s.z * SC, s.w * SC);

        float* f = feats + (size_t)g * FIVE_D + 4 * c;
        *reinterpret_cast<float4*>(f)         = ssc;
        *reinterpret_cast<float4*>(f + D)     = mean;
        *reinterpret_cast<float4*>(f + 2 * D) = mn;
        *reinterpret_cast<float4*>(f + 3 * D) = mx;
        *reinterpret_cast<float4*>(f + 4 * D) = sd;
    }
}

// ---------------- Kernel 3: out[G,128] = feats[G,640] @ W[640,128] + b ----------------
// One wave per 8 rows; lane owns cols (lane, lane+64). feats reads are wave-uniform
// broadcast float4 loads (1 L1 line/instr). Register-double-buffered k-loop (A/B)
// hides L1 latency under the 64-FMA block. W L1 traffic: 1250 waves x 327KB = 400MB.
#define LOADK(SUF, kk) do {                                                              \
    const int k_ = (kk);                                                                 \
    _Pragma("unroll")                                                                    \
    for (int r = 0; r < GW; ++r)                                                         \
        f##SUF[r] = *reinterpret_cast<const float4*>(fr[r] + k_);                        \
    _Pragma("unroll")                                                                    \
    for (int j = 0; j < 4; ++j) {                                                        \
        w##SUF##0[j] = Wp0[(size_t)(k_ + j) * NOUT];                                     \
        w##SUF##1[j] = Wp1[(size_t)(k_ + j) * NOUT];                                     \
    }                                                                                    \
} while (0)

#define FMAK(SUF) do {                                                                   \
    _Pragma("unroll")                                                                    \
    for (int r = 0; r < GW; ++r) {                                                       \
        a0[r] = fmaf(f##SUF[r].x, w##SUF##0[0], a0[r]);                                  \
        a1[r] = fmaf(f##SUF[r].x, w##SUF##1[0], a1[r]);                                  \
        a0[r] = fmaf(f##SUF[r].y, w##SUF##0[1], a0[r]);                                  \
        a1[r] = fmaf(f##SUF[r].y, w##SUF##1[1], a1[r]);                                  \
        a0[r] = fmaf(f##SUF[r].z, w##SUF##0[2], a0[r]);                                  \
        a1[r] = fmaf(f##SUF[r].z, w##SUF##1[2], a1[r]);                                  \
        a0[r] = fmaf(f##SUF[r].w, w##SUF##0[3], a0[r]);                                  \
        a1[r] = fmaf(f##SUF[r].w, w##SUF##1[3], a1[r]);                                  \
    }                                                                                    \
} while (0)

__global__ __launch_bounds__(64) void gemm_kernel(const float* __restrict__ feats,
                                                  const float* __restrict__ W,
                                                  const float* __restrict__ b,
                                                  float* __restrict__ out, int G) {
    const int lane = threadIdx.x;
    const int g0 = blockIdx.x * GW;
    if (g0 >= G) return;

    const float* fr[GW];
    #pragma unroll
    for (int r = 0; r < GW; ++r)
        fr[r] = feats + (size_t)min(g0 + r, G - 1) * FIVE_D;

    const float* Wp0 = W + lane;
    const float* Wp1 = W + 64 + lane;

    float a0[GW], a1[GW];
    #pragma unroll
    for (int r = 0; r < GW; ++r) { a0[r] = 0.f; a1[r] = 0.f; }

    float4 fA[GW], fB[GW];
    float wA0[4], wA1[4], wB0[4], wB1[4];

    LOADK(A, 0);
    for (int k = 0; k < FIVE_D; k += 8) {
        LOADK(B, k + 4);
        FMAK(A);
        if (k + 8 < FIVE_D) LOADK(A, k + 8);
        FMAK(B);
    }

    const float b0 = b[lane];
    const float b1 = b[64 + lane];
    #pragma unroll
    for (int r = 0; r < GW; ++r) {
        const int g = g0 + r;
        if (g < G) {
            out[(size_t)g * NOUT + lane]      = a0[r] + b0;
            out[(size_t)g * NOUT + 64 + lane] = a1[r] + b1;
        }
    }
}

extern "C" void kernel_launch(void* const* d_in, const int* in_sizes, int n_in,
                              void* d_out, int out_size, void* d_ws, size_t ws_size,
                              hipStream_t stream) {
    const float* x     = (const float*)d_in[0];
    const int*   batch = (const int*)d_in[1];
    const float* W     = (const float*)d_in[2];
    const float* b     = (const float*)d_in[3];
    float* out = (float*)d_out;

    const int N = in_sizes[0] / D;       // 500000
    const int G = out_size / NOUT;       // 10000

    int*   offs  = (int*)d_ws;                               // (G+1) ints
    float* feats = (float*)((char*)d_ws + 65536);            // G * 640 floats

    seg_offsets_kernel<<<(G + 1 + 255) / 256, 256, 0, stream>>>(batch, offs, N, G);
    seg_stats_kernel<<<G, 64, 0, stream>>>(x, offs, feats);
    gemm_kernel<<<(G + GW - 1) / GW, 64, 0, stream>>>(feats, W, b, out, G);
}